// Round 9
// baseline (132.517 us; speedup 1.0000x reference)
//
#include <hip/hip_runtime.h>
#include <math.h>

#define NP 4
#define NN 8192
#define NM 8192

// ws layout (float units):
//   TP:   packed targets [8 z][8192 t] float4 {-2tx,-2ty,-2tz,|t|^2} = 2 MB
//   MINS: [8 z][8192 q] floats, atomicMin'd (INF-init by prep)       = 256 KB
#define TP_OFF   0
#define MINS_OFF 524288

#define TQ 16       // queries per thread
#define QT 4096     // queries per block (256 * TQ)
#define SPLITS 64   // target splits -> grid (2,64,8) = 1024 blocks = 4/CU
#define SPAN 128    // targets per block

__device__ inline float min3f(float a, float b, float c) {
    float d;
    asm("v_min3_f32 %0, %1, %2, %3" : "=v"(d) : "v"(a), "v"(b), "v"(c));
    return d;
}

__device__ inline void make_transform(const float* __restrict__ quat,
                                      const float* __restrict__ tra,
                                      int p, float T[12]) {
    float q0 = quat[p * 4 + 0], q1 = quat[p * 4 + 1];
    float q2 = quat[p * 4 + 2], q3 = quat[p * 4 + 3];
    float inv = 1.0f / sqrtf(q0 * q0 + q1 * q1 + q2 * q2 + q3 * q3);
    float a = q0 * inv, b = q1 * inv, c = q2 * inv, d = q3 * inv;
    T[0] = 1.0f - 2.0f * c * c - 2.0f * d * d;
    T[1] = 2.0f * b * c - 2.0f * a * d;
    T[2] = 2.0f * a * c + 2.0f * b * d;
    T[3] = tra[p * 3 + 0];
    T[4] = 2.0f * b * c + 2.0f * a * d;
    T[5] = 1.0f - 2.0f * b * b - 2.0f * d * d;
    T[6] = 2.0f * c * d - 2.0f * a * b;
    T[7] = tra[p * 3 + 1];
    T[8] = 2.0f * b * d - 2.0f * a * c;
    T[9] = 2.0f * a * b + 2.0f * c * d;
    T[10] = 1.0f - 2.0f * b * b - 2.0f * c * c;
    T[11] = tra[p * 3 + 2];
}

// 256 blocks x 256 threads over 65536 points: packed target float4 per point
// (in its target slice), INF mins init, transforms out, out[0]=0.
__global__ __launch_bounds__(256) void prep_kernel(
    const float* __restrict__ cam, const float* __restrict__ cad,
    const float* __restrict__ quat, const float* __restrict__ tra,
    float* __restrict__ ws, float* __restrict__ out) {
    int idx = blockIdx.x * 256 + threadIdx.x;  // [0, 65536)
    int i = idx & 8191;
    int p = (idx >> 13) & 3;
    bool is_cad = idx < 32768;

    const float* src = (is_cad ? cad : cam) + ((size_t)p * 8192 + i) * 3;
    float x = src[0], y = src[1], z = src[2];
    float vx, vy, vz;
    if (is_cad) {
        float T[12];
        make_transform(quat, tra, p, T);
        vx = fmaf(T[0], x, fmaf(T[1], y, fmaf(T[2], z, T[3])));
        vy = fmaf(T[4], x, fmaf(T[5], y, fmaf(T[6], z, T[7])));
        vz = fmaf(T[8], x, fmaf(T[9], y, fmaf(T[10], z, T[11])));
    } else {
        vx = x; vy = y; vz = z;
    }
    float nrm = vx * vx + vy * vy + vz * vz;

    // roles: slice z=2p+role; role0: queries=cad_t, targets=cam; role1 swapped
    int zt = is_cad ? 2 * p + 1 : 2 * p;  // slice where this point is a TARGET
    ((float4*)(ws + TP_OFF))[(size_t)zt * 8192 + i] =
        make_float4(-2.0f * vx, -2.0f * vy, -2.0f * vz, nrm);

    ((unsigned int*)(ws + MINS_OFF))[idx] = 0x7f800000u;  // +INF

    if (idx < 64) {
        int p2 = idx >> 4;
        int rr = (idx >> 2) & 3;
        int c = idx & 3;
        float T2[12];
        make_transform(quat, tra, p2, T2);
        float v;
        if (rr == 3)
            v = (c == 3) ? 1.0f : 0.0f;
        else
            v = T2[rr * 4 + c];
        out[1 + idx] = v;
    } else if (idx == 64) {
        out[0] = 0.0f;
    }
}

// grid (2, 64, 8) = 1024 blocks x 256 thr = exactly 4 blocks/CU (1 round).
// SGPR-target inner loop: target float4s are read via a BLOCK-UNIFORM index
// -> compiler emits s_load into SGPRs; v_fma consumes the SGPR directly
// (1 sgpr/instr rule: the |t|^2 addend gets one hoisted v_mov per target).
// NO LDS, NO shuffles: R1-R4 showed VALUBusy pinned at 57-66% across 25-53%
// occupancy = VALU queuing against the CU-shared LDS pipe; this deletes it.
// Per 2 targets x 16 queries: 2 mov + 96 fma + 16 min3 = 3.56 lane-ops/pair
// (floor 24.3 us). Epilogue: fire-and-forget atomicMin (measured free).
__global__ __launch_bounds__(256, 4)
void chamfer_kernel(const float* __restrict__ cam, const float* __restrict__ cad,
                    const float* __restrict__ quat, const float* __restrict__ tra,
                    float* __restrict__ ws) {
    int tid = threadIdx.x;
    int z = blockIdx.z;
    int p = z >> 1;
    int role = z & 1;

    // ---- load + transform TQ queries per thread ----
    float T[12];
    make_transform(quat, tra, p, T);
    int q0 = blockIdx.x * QT + tid;
    const float* qbase = (role ? cam : cad) + (size_t)p * 8192 * 3;
    float qx[TQ], qy[TQ], qz[TQ], hq[TQ], tmin[TQ];
    const float INF = __uint_as_float(0x7f800000u);
#pragma unroll
    for (int k = 0; k < TQ; ++k) {
        const float* s = qbase + (size_t)(q0 + k * 256) * 3;
        float x = s[0], y = s[1], zz = s[2];
        float vx, vy, vz;
        if (!role) {  // queries = cad_t
            vx = fmaf(T[0], x, fmaf(T[1], y, fmaf(T[2], zz, T[3])));
            vy = fmaf(T[4], x, fmaf(T[5], y, fmaf(T[6], zz, T[7])));
            vz = fmaf(T[8], x, fmaf(T[9], y, fmaf(T[10], zz, T[11])));
        } else {      // queries = cam raw
            vx = x; vy = y; vz = zz;
        }
        qx[k] = vx; qy[k] = vy; qz[k] = vz;
        hq[k] = vx * vx + vy * vy + vz * vz;
        tmin[k] = INF;
    }

    // ---- SGPR-target main loop: 64 groups of 2 targets ----
    const float4* TPz = (const float4*)(ws + TP_OFF) + (size_t)z * 8192 +
                        blockIdx.y * SPAN;  // block-uniform base
#pragma unroll 2
    for (int g = 0; g < SPAN / 2; ++g) {
        float4 t0 = TPz[2 * g];      // uniform index -> s_load, stays in SGPRs
        float4 t1 = TPz[2 * g + 1];
        float a0[TQ], a1[TQ];
#pragma unroll
        for (int k = 0; k < TQ; ++k)
            a0[k] = fmaf(t0.z, qz[k], fmaf(t0.y, qy[k], fmaf(t0.x, qx[k], t0.w)));
#pragma unroll
        for (int k = 0; k < TQ; ++k)
            a1[k] = fmaf(t1.z, qz[k], fmaf(t1.y, qy[k], fmaf(t1.x, qx[k], t1.w)));
#pragma unroll
        for (int k = 0; k < TQ; ++k)
            tmin[k] = min3f(tmin[k], a0[k], a1[k]);
    }

    unsigned int* mins = (unsigned int*)(ws + MINS_OFF) + (size_t)z * 8192;
#pragma unroll
    for (int k = 0; k < TQ; ++k) {
        float d2 = fmaxf(hq[k] + tmin[k], 0.0f);
        atomicMin(&mins[q0 + k * 256], __float_as_uint(d2));
    }
}

// 256 blocks x 256 threads: one (z, q) item per thread over the 256 KB mins
// array, then sqrt, weight, hierarchical sum into out[0].
__global__ __launch_bounds__(256) void finalize_kernel(
    const float* __restrict__ mins, const float* __restrict__ w,
    float* __restrict__ out) {
    int i = blockIdx.x * 256 + threadIdx.x;  // [0, 65536)
    int tid = threadIdx.x;

    float m = mins[i];
    float acc = w[i >> 14] * sqrtf(m);  // p = (i>>13)>>1

#pragma unroll
    for (int off = 32; off > 0; off >>= 1) acc += __shfl_down(acc, off, 64);

    __shared__ float wsum[4];
    if ((tid & 63) == 0) wsum[tid >> 6] = acc;
    __syncthreads();
    if (tid == 0) {
        float blocksum = (wsum[0] + wsum[1] + wsum[2] + wsum[3]) * (1.0f / 8192.0f);
        atomicAdd(out, blocksum);
    }
}

extern "C" void kernel_launch(void* const* d_in, const int* in_sizes, int n_in,
                              void* d_out, int out_size, void* d_ws, size_t ws_size,
                              hipStream_t stream) {
    const float* cam = (const float*)d_in[0];   // (P, N, 3)
    const float* cad = (const float*)d_in[1];   // (P, M, 3)
    const float* w = (const float*)d_in[2];     // (P,)
    const float* quat = (const float*)d_in[3];  // (P, 4)
    const float* tra = (const float*)d_in[4];   // (P, 3, 1)
    float* out = (float*)d_out;
    float* ws = (float*)d_ws;

    prep_kernel<<<256, 256, 0, stream>>>(cam, cad, quat, tra, ws, out);

    dim3 grid(NM / QT, SPLITS, 2 * NP);
    chamfer_kernel<<<grid, 256, 0, stream>>>(cam, cad, quat, tra, ws);

    finalize_kernel<<<256, 256, 0, stream>>>(ws + MINS_OFF, w, out);
}

// Round 10
// 111.954 us; speedup vs baseline: 1.1837x; 1.1837x over previous
//
#include <hip/hip_runtime.h>
#include <math.h>

#define NP 4
#define NN 8192
#define NM 8192

// ws layout: mins [8 z][8192 q] floats at offset 0 (256 KB), atomicMin'd,
// poisoned 0x7f7f7f7f by memset node.
#define TQ 16       // queries per thread (halves LDS-pipe load vs TQ=8)
#define QT 4096     // queries per block (256 * TQ)
#define SPLITS 64   // target splits -> grid (2,64,8) = 1024 blocks = 4/CU
#define SPAN 128    // targets per block

__device__ inline float min3f(float a, float b, float c) {
    float d;
    asm("v_min3_f32 %0, %1, %2, %3" : "=v"(d) : "v"(a), "v"(b), "v"(c));
    return d;
}

__device__ inline void make_transform(const float* __restrict__ quat,
                                      const float* __restrict__ tra,
                                      int p, float T[12]) {
    float q0 = quat[p * 4 + 0], q1 = quat[p * 4 + 1];
    float q2 = quat[p * 4 + 2], q3 = quat[p * 4 + 3];
    float inv = 1.0f / sqrtf(q0 * q0 + q1 * q1 + q2 * q2 + q3 * q3);
    float a = q0 * inv, b = q1 * inv, c = q2 * inv, d = q3 * inv;
    T[0] = 1.0f - 2.0f * c * c - 2.0f * d * d;
    T[1] = 2.0f * b * c - 2.0f * a * d;
    T[2] = 2.0f * a * c + 2.0f * b * d;
    T[3] = tra[p * 3 + 0];
    T[4] = 2.0f * b * c + 2.0f * a * d;
    T[5] = 1.0f - 2.0f * b * b - 2.0f * d * d;
    T[6] = 2.0f * c * d - 2.0f * a * b;
    T[7] = tra[p * 3 + 1];
    T[8] = 2.0f * b * d - 2.0f * a * c;
    T[9] = 2.0f * a * b + 2.0f * c * d;
    T[10] = 1.0f - 2.0f * b * b - 2.0f * c * c;
    T[11] = tra[p * 3 + 2];
}

// Fused prep+chamfer. grid (2, 64, 8) = 1024 blocks = 4 blocks/CU.
// WHY TQ=16 + LDS (consolidated from R1-R9 counters):
//  - VALU floor = 24 us (3 fma + 0.5 min3 per pair; pk_fma cycle-neutral).
//  - TQ=8 pinned at 46-47us / VALUBusy ~63% across 25-53% occupancy: the
//    CU-shared LDS pipe ran ~86-100% loaded (16 waves x 2 ds_read_b128 per
//    112-cy window) -> waves queue on LDS, not on occupancy.
//  - TQ=16 doubles compute per LDS byte: 32B per 224 cy -> ~43% pipe load.
//  - R4/R9 TQ=16 attempts failed in CODEGEN (ext-vector/asm arrays ->
//    scratch: VGPR_Count 52/44, FETCH +1.7GB). This version uses the
//    R1-proven scalar-array pattern only: plain float[16], plain fmaf,
//    full static unrolls, no op_sel asm, no SGPR operand tricks.
// launch_bounds(256,2): VGPR cap 256, no forced diet; ~104 live regs ->
// 16 waves/CU by the 128-VGPR bin, matching the 4 blocks/CU grid.
// Epilogue: fire-and-forget atomicMin (measured free, R0 vs R1).
__global__ __launch_bounds__(256, 2)
void chamfer_kernel(const float* __restrict__ cam, const float* __restrict__ cad,
                    const float* __restrict__ quat, const float* __restrict__ tra,
                    float* __restrict__ ws, float* __restrict__ out) {
    int tid = threadIdx.x;
    int z = blockIdx.z;
    int p = z >> 1;
    int role = z & 1;

    float T[12];
    make_transform(quat, tra, p, T);

    if (blockIdx.x == 0 && blockIdx.y == 0 && blockIdx.z == 0) {
        if (tid < 64) {
            int p2 = tid >> 4;
            int r = (tid >> 2) & 3;
            int c = tid & 3;
            float T2[12];
            make_transform(quat, tra, p2, T2);
            float v;
            if (r == 3)
                v = (c == 3) ? 1.0f : 0.0f;
            else
                v = T2[r * 4 + c];
            out[1 + tid] = v;
        } else if (tid == 64) {
            out[0] = 0.0f;
        }
    }

    // ---- stage SPAN targets into LDS as packed float4 {x,y,z,ht} ----
    // role==0: queries = cad_t, targets = cam ; role==1: queries = cam,
    // targets = cad_t. Broadcast-read later (all lanes same addr: conflict-free).
    __shared__ float4 sT[SPAN];  // 2 KB
    if (tid < SPAN) {
        const float* src = (role ? cad : cam) +
                           ((size_t)p * 8192 + blockIdx.y * SPAN + tid) * 3;
        float x = src[0], y = src[1], zz = src[2];
        float vx, vy, vz;
        if (role) {
            vx = fmaf(T[0], x, fmaf(T[1], y, fmaf(T[2], zz, T[3])));
            vy = fmaf(T[4], x, fmaf(T[5], y, fmaf(T[6], zz, T[7])));
            vz = fmaf(T[8], x, fmaf(T[9], y, fmaf(T[10], zz, T[11])));
        } else {
            vx = x; vy = y; vz = zz;
        }
        float ht = 0.5f * (vx * vx + vy * vy + vz * vz);
        sT[tid] = make_float4(vx, vy, vz, ht);
    }

    // ---- load + transform TQ queries per thread (negated for fma form) ----
    const float INF = __uint_as_float(0x7f800000u);
    int q0 = blockIdx.x * QT + tid;
    const float* qbase = (role ? cam : cad) + (size_t)p * 8192 * 3;
    float nqx[TQ], nqy[TQ], nqz[TQ], hq[TQ], tmin[TQ];
#pragma unroll
    for (int k = 0; k < TQ; ++k) {
        const float* s = qbase + (size_t)(q0 + k * 256) * 3;
        float x = s[0], y = s[1], zz = s[2];
        float vx, vy, vz;
        if (!role) {
            vx = fmaf(T[0], x, fmaf(T[1], y, fmaf(T[2], zz, T[3])));
            vy = fmaf(T[4], x, fmaf(T[5], y, fmaf(T[6], zz, T[7])));
            vz = fmaf(T[8], x, fmaf(T[9], y, fmaf(T[10], zz, T[11])));
        } else {
            vx = x; vy = y; vz = zz;
        }
        nqx[k] = -vx;
        nqy[k] = -vy;
        nqz[k] = -vz;
        hq[k] = 0.5f * (vx * vx + vy * vy + vz * vz);
        tmin[k] = INF;
    }
    __syncthreads();

    // ---- main loop: 64 pairs of targets, distance-1 prefetch ----
    // per pair: 2 ds_read_b128 (broadcast) + 96 fma + 16 min3 = 224 cy VALU
    float4 c0 = sT[0], c1 = sT[1];
#pragma unroll 2
    for (int g = 0; g < SPAN / 2; ++g) {
        int gn = (g + 1) & (SPAN / 2 - 1);  // last iter reloads pair 0
        float4 n0 = sT[2 * gn];
        float4 n1 = sT[2 * gn + 1];
#pragma unroll
        for (int k = 0; k < TQ; ++k) {
            float a0 = fmaf(nqz[k], c0.z,
                       fmaf(nqy[k], c0.y, fmaf(nqx[k], c0.x, c0.w)));
            float a1 = fmaf(nqz[k], c1.z,
                       fmaf(nqy[k], c1.y, fmaf(nqx[k], c1.x, c1.w)));
            tmin[k] = min3f(tmin[k], a0, a1);
        }
        c0 = n0;
        c1 = n1;
    }

    unsigned int* mins = (unsigned int*)ws + (size_t)z * 8192;
#pragma unroll
    for (int k = 0; k < TQ; ++k) {
        float d2 = 2.0f * (hq[k] + tmin[k]);
        d2 = fmaxf(d2, 0.0f);
        atomicMin(&mins[q0 + k * 256], __float_as_uint(d2));
    }
}

// 256 blocks x 256 threads: one (z, q) item per thread over the 256 KB mins
// array, then sqrt, weight, hierarchical sum into out[0]. (R9-proven.)
__global__ __launch_bounds__(256) void finalize_kernel(
    const float* __restrict__ mins, const float* __restrict__ w,
    float* __restrict__ out) {
    int i = blockIdx.x * 256 + threadIdx.x;  // [0, 65536)
    int tid = threadIdx.x;

    float m = mins[i];
    float acc = w[i >> 14] * sqrtf(m);  // p = (i>>13)>>1

#pragma unroll
    for (int off = 32; off > 0; off >>= 1) acc += __shfl_down(acc, off, 64);

    __shared__ float wsum[4];
    if ((tid & 63) == 0) wsum[tid >> 6] = acc;
    __syncthreads();
    if (tid == 0) {
        float blocksum = (wsum[0] + wsum[1] + wsum[2] + wsum[3]) * (1.0f / 8192.0f);
        atomicAdd(out, blocksum);
    }
}

extern "C" void kernel_launch(void* const* d_in, const int* in_sizes, int n_in,
                              void* d_out, int out_size, void* d_ws, size_t ws_size,
                              hipStream_t stream) {
    const float* cam = (const float*)d_in[0];   // (P, N, 3)
    const float* cad = (const float*)d_in[1];   // (P, M, 3)
    const float* w = (const float*)d_in[2];     // (P,)
    const float* quat = (const float*)d_in[3];  // (P, 4)
    const float* tra = (const float*)d_in[4];   // (P, 3, 1)
    float* out = (float*)d_out;
    float* ws = (float*)d_ws;

    // Poison mins with 0x7f7f7f7f (= 3.39e38, > any real distance^2).
    hipMemsetAsync(ws, 0x7f, (size_t)65536 * sizeof(float), stream);

    dim3 grid(NM / QT, SPLITS, 2 * NP);
    chamfer_kernel<<<grid, 256, 0, stream>>>(cam, cad, quat, tra, ws, out);

    finalize_kernel<<<256, 256, 0, stream>>>(ws, w, out);
}